// Round 6
// baseline (733.491 us; speedup 1.0000x reference)
//
#include <hip/hip_runtime.h>
#include <stdint.h>
#include <stddef.h>

// ---------------------------------------------------------------------------
// Round 6: 3 chained GEMMs (gather fused into GEMM-1), 32x32x16 MFMA, 128x128
// tile, BK=64. NEW: X and Wt live in K-PANEL layout = exactly the order the
// consumer stages them into LDS. Slot within a (128-row x 64-k) panel:
//   s = (c>>1)*256 + (row>>5)*64 + (c&1)*32 + (row&31),  c = 16B-col 0..7
// -> staging is 4 contiguous 16KB streams, and fragment ds_read_b128 is
// addr = base + lane*16 (affine lane-contiguous, conflict-free by
// construction). R4/R5's 6.29e6 LDS conflicts (= +4cy on EVERY frag read,
// present in all variants incl. no-epilogue-LDS MODE0) were the XOR-swizzled
// frag reads; this deletes them. Epilogues: MODE0 = LDS repack (stride 152
// shorts, odd 16B-blocks -> rotating banks) + coalesced panel-order ushort8
// stores; FINAL = LDS repack + sWo-staged @Wo reduction + atomicAdd.
// ---------------------------------------------------------------------------

typedef __attribute__((ext_vector_type(8))) short short8;
typedef __attribute__((ext_vector_type(16))) float f32x16;
typedef __attribute__((ext_vector_type(4))) float floatv4;
typedef __attribute__((ext_vector_type(8))) unsigned short ushort8;

#define GLOAD_LDS16(g, l)                                                      \
  __builtin_amdgcn_global_load_lds(                                            \
      (const __attribute__((address_space(1))) void*)(g),                      \
      (__attribute__((address_space(3))) void*)(l), 16, 0, 0)

__device__ __forceinline__ unsigned short f2bf(float f) {
  unsigned int u = __float_as_uint(f);
  u += 0x7fffu + ((u >> 16) & 1u);  // RNE
  return (unsigned short)(u >> 16);
}
__device__ __forceinline__ float bf2f(unsigned short s) {
  return __uint_as_float(((unsigned int)s) << 16);
}

#define NNODES 100000
#define MTOT   300000
#define HD     512
#define NH     50000
#define LSTR   152   // L row stride in shorts: 304B = 19 x 16B (odd -> rotate)

// --- Wt in panel layout: per layer, per (nb,kt) panel of 1024 slots ---------
__global__ __launch_bounds__(256) void prep_w(const float* __restrict__ W1,
                                              const float* __restrict__ W2,
                                              const float* __restrict__ W3,
                                              unsigned short* __restrict__ Wt) {
  int t = blockIdx.x * 256 + threadIdx.x;  // < 3*512*512
  int layer = t >> 18;
  int r = t & 262143;
  int e = r & 7;
  int q16 = r >> 3;
  int s = q16 & 1023;
  int blk = q16 >> 10;        // 0..31
  int nb = blk >> 3, kt = blk & 7;
  int c = ((s >> 8) << 1) | ((s >> 5) & 1);
  int row = ((s >> 6) & 3) * 32 + (s & 31);
  int n = nb * 128 + row;
  int k = kt * 64 + c * 8 + e;
  const float* W = layer == 0 ? W1 : (layer == 1 ? W2 : W3);
  Wt[t] = f2bf(W[k * 512 + n]);
}

// --- hb = bf16(h) [50000 x 128], row-major ----------------------------------
__global__ __launch_bounds__(256) void prep_hb(const float* __restrict__ h,
                                               unsigned short* __restrict__ hb) {
  int t = blockIdx.x * 256 + threadIdx.x;  // < NH*16
  int v = t >> 4, c8 = (t & 15) * 8;
  const floatv4* hp = (const floatv4*)(h + (size_t)v * 128 + c8);
  floatv4 f0 = hp[0], f1 = hp[1];
  ushort8 o;
#pragma unroll
  for (int e = 0; e < 4; ++e) {
    o[e] = f2bf(f0[e]);
    o[4 + e] = f2bf(f1[e]);
  }
  *(ushort8*)(hb + (size_t)v * 128 + c8) = o;
}

__global__ __launch_bounds__(256) void init_out(float* __restrict__ out,
                                                const float* __restrict__ bo) {
  int t = blockIdx.x * 256 + threadIdx.x;
  if (t < 2 * NNODES) out[t] = bo[t & 1];
}

// --- GEMM: 128x128 tile, BK=64, K=512, 32x32x16 MFMA, panel-layout I/O ------
template <int GATHER, int FINAL>
__global__ __launch_bounds__(256, 4) void gemm_k(
    const unsigned short* __restrict__ A,   // GATHER ? hb(row-major) : X panel
    const int* __restrict__ idx,
    const unsigned short* __restrict__ Wt,  // panel layout
    const float* __restrict__ bias,
    unsigned short* __restrict__ Xout,      // panel layout
    float* __restrict__ out, const float* __restrict__ Wo,
    int mchunk0) {
  __shared__ __align__(16) char smem[39936];
  char* sA = smem;                       // 16384
  char* sB = smem + 16384;               // 16384
  int* sIdx = (int*)(smem + 32768);      // 2048
  float* sWo = (float*)(smem + 38912);   // 1024 (epilogue only)

  const int t = threadIdx.x;
  int bx = blockIdx.x;
  // XCD swizzle: 4 col-blocks of one row-block land on one XCD.
  int xcd = bx & 7, tq = bx >> 3;
  int cbk = tq & 3;
  int rb = xcd + ((tq >> 2) << 3);
  int n0 = cbk * 128;
  int rb8 = rb * 8;
  int w = t >> 6, l = t & 63;
  int wmq = (w >> 1) * 2, wnq = (w & 1) * 2;   // row-block/32 bases
  int m32 = l & 31, half = l >> 5;

  if (GATHER) {
    if (t < 128) {
      int m = mchunk0 + rb * 128 + t;
      unsigned um = (unsigned)m;
      unsigned n = um / 3u;
      int p = (int)(um - n * 3u);
      if (n >= NNODES) n = 0;  // padded tail rows: junk, guarded at output
      const unsigned pk0 = 0x320u, pk1 = 0x111u, pk2 = 0x032u, pk3 = 0x203u;
      int sh = p * 4;
      sIdx[t * 4 + 0] = idx[n * 4 + ((pk0 >> sh) & 0xFu)];
      sIdx[t * 4 + 1] = idx[n * 4 + ((pk1 >> sh) & 0xFu)];
      sIdx[t * 4 + 2] = idx[n * 4 + ((pk2 >> sh) & 0xFu)];
      sIdx[t * 4 + 3] = idx[n * 4 + ((pk3 >> sh) & 0xFu)];
    }
    __syncthreads();
  }

  f32x16 acc[2][2];
#pragma unroll
  for (int i = 0; i < 2; ++i)
#pragma unroll
    for (int j = 0; j < 2; ++j)
#pragma unroll
      for (int r = 0; r < 16; ++r) acc[i][j][r] = 0.f;

  for (int kt = 0; kt < 8; ++kt) {
    if (GATHER) {
      int jn = kt >> 1;
      int base = (kt & 1) * 64;
      int row = ((t >> 6) & 3) * 32 + (t & 31);
      int src = sIdx[row * 4 + jn];
      int hbit = (t >> 5) & 1;
#pragma unroll
      for (int i = 0; i < 4; ++i) {
        int c = (i << 1) | hbit;
        GLOAD_LDS16(A + (size_t)src * 128 + base + c * 8,
                    sA + (i * 256 + t) * 16);
      }
    } else {
      const unsigned short* ga = A + ((size_t)(rb8 + kt) * 1024 + t) * 8;
#pragma unroll
      for (int i = 0; i < 4; ++i)
        GLOAD_LDS16(ga + (size_t)i * 2048, sA + (i * 256 + t) * 16);
    }
    {
      const unsigned short* gb = Wt + ((size_t)(cbk * 8 + kt) * 1024 + t) * 8;
#pragma unroll
      for (int i = 0; i < 4; ++i)
        GLOAD_LDS16(gb + (size_t)i * 2048, sB + (i * 256 + t) * 16);
    }
    __syncthreads();
#pragma unroll
    for (int ks = 0; ks < 4; ++ks) {
      short8 af[2], bfr[2];
#pragma unroll
      for (int i = 0; i < 2; ++i)
        af[i] = *(const short8*)(sA + (ks * 256 + (wmq + i) * 64 + l) * 16);
#pragma unroll
      for (int j = 0; j < 2; ++j)
        bfr[j] = *(const short8*)(sB + (ks * 256 + (wnq + j) * 64 + l) * 16);
#pragma unroll
      for (int i = 0; i < 2; ++i)
#pragma unroll
        for (int j = 0; j < 2; ++j)
          acc[i][j] = __builtin_amdgcn_mfma_f32_32x32x16_bf16(af[i], bfr[j],
                                                              acc[i][j], 0, 0, 0);
    }
    __syncthreads();
  }

  // Epilogue. 32x32 C/D: col = lane&31, row = (reg&3) + 8*(reg>>2) + 4*half.
  unsigned short* L = (unsigned short*)smem;
  if (FINAL && t < 256) sWo[t] = Wo[n0 * 2 + t];
#pragma unroll
  for (int i = 0; i < 2; ++i)
#pragma unroll
    for (int j = 0; j < 2; ++j) {
      int coll = wnq * 32 + j * 32 + m32;
      float bv = bias[n0 + coll];
#pragma unroll
      for (int r = 0; r < 16; ++r) {
        int rowl = wmq * 32 + i * 32 + (r & 3) + 8 * (r >> 2) + 4 * half;
        float v = fmaxf(acc[i][j][r] + bv, 0.f);
        L[rowl * LSTR + coll] = f2bf(v);
      }
    }
  __syncthreads();

  if (!FINAL) {
    // panel-order coalesced stores: consecutive t -> consecutive 16B slots
#pragma unroll
    for (int v = 0; v < 8; ++v) {
      int chunk = v * 256 + t;          // 0..2047
      int ktsel = chunk >> 10;
      int s = chunk & 1023;
      int ks_l = s >> 8;
      int rowhi = (s >> 6) & 3;
      int hb_ = (s >> 5) & 1;
      int row = rowhi * 32 + (s & 31);
      int col_local = ktsel * 64 + (((ks_l << 1) | hb_) << 3);
      ushort8 val = *(const ushort8*)(L + row * LSTR + col_local);
      *(ushort8*)(Xout + ((size_t)(rb8 + 2 * cbk + ktsel) * 1024 + s) * 8) = val;
    }
  } else {
    int r2 = t >> 1, jo = t & 1;
    int grow = mchunk0 + rb * 128 + r2;
    if (grow < MTOT) {
      const unsigned short* Lr = L + r2 * LSTR;
      float s = 0.f;
#pragma unroll
      for (int cc = 0; cc < 128; cc += 2) {
        unsigned int pair = *(const unsigned int*)(Lr + cc);
        s += bf2f((unsigned short)(pair & 0xffffu)) * sWo[2 * cc + jo];
        s += bf2f((unsigned short)(pair >> 16)) * sWo[2 * cc + 2 + jo];
      }
      int node = grow / 3;
      atomicAdd(out + node * 2 + jo, s);
    }
  }
}

extern "C" void kernel_launch(void* const* d_in, const int* in_sizes, int n_in,
                              void* d_out, int out_size, void* d_ws,
                              size_t ws_size, hipStream_t stream) {
  const float* h  = (const float*)d_in[0];
  const int*   ix = (const int*)d_in[1];
  const float* W1 = (const float*)d_in[2];
  const float* b1 = (const float*)d_in[3];
  const float* W2 = (const float*)d_in[4];
  const float* b2 = (const float*)d_in[5];
  const float* W3 = (const float*)d_in[6];
  const float* b3 = (const float*)d_in[7];
  const float* Wo = (const float*)d_in[8];
  const float* bo = (const float*)d_in[9];
  float* out = (float*)d_out;

  unsigned short* ws = (unsigned short*)d_ws;
  unsigned short* Wt = ws;                  // 3*512*512 shorts (panel)
  unsigned short* hb = Wt + 786432;         // 50000*128 shorts (row-major)
  unsigned short* bufs = hb + 6400000;
  const size_t baseBytes = (786432ull + 6400000ull) * 2;

  // nodes per chunk: multiple of 2048 -> rows%6144==0 -> RB%48==0 (RB%8==0)
  size_t avail = ws_size > baseBytes ? ws_size - baseBytes : 0;
  size_t ncap = avail / (2ull * 3 * HD * sizeof(unsigned short));
  size_t nc = (ncap / 2048) * 2048;
  if (nc > 32768) nc = 32768;
  if (nc == 0) nc = 2048;  // best effort
  unsigned short* X1 = bufs;                // panel layout
  unsigned short* X2 = X1 + nc * 3 * HD;    // panel layout

  prep_w<<<3072, 256, 0, stream>>>(W1, W2, W3, Wt);
  prep_hb<<<NH * 16 / 256, 256, 0, stream>>>(h, hb);
  init_out<<<(2 * NNODES + 255) / 256, 256, 0, stream>>>(out, bo);

  for (size_t n0c = 0; n0c < NNODES; n0c += nc) {
    size_t remn = (size_t)NNODES - n0c;
    size_t ncp = remn < nc ? ((remn + 2047) / 2048) * 2048 : nc;
    int rows = (int)(ncp * 3);
    int RB = rows / 128;
    int m0 = (int)(3 * n0c);
    gemm_k<1, 0><<<RB * 4, 256, 0, stream>>>(hb, ix, Wt, b1, X1, nullptr,
                                             nullptr, m0);
    gemm_k<0, 0><<<RB * 4, 256, 0, stream>>>(X1, nullptr, Wt + 262144, b2, X2,
                                             nullptr, nullptr, m0);
    gemm_k<0, 1><<<RB * 4, 256, 0, stream>>>(X2, nullptr, Wt + 524288, b3,
                                             nullptr, out, Wo, m0);
  }
}

// Round 7
// 652.901 us; speedup vs baseline: 1.1234x; 1.1234x over previous
//
#include <hip/hip_runtime.h>
#include <stdint.h>
#include <stddef.h>

// ---------------------------------------------------------------------------
// Round 7: 3 chained GEMMs, 32x32x16 MFMA, 128x128 tile, BK=64.
// vs R6: A-frags bypass LDS entirely in non-GATHER gemms (A-rows are wave-
// private -> no reuse; panel layout makes the frag load a lane-contiguous
// 1KB global_load_dwordx4, issued BEFORE B-staging so the barrier vmcnt(0)
// absorbs the latency). Only B (shared by 4 waves) is staged to LDS.
// This halves the per-kt LDS-pipe load (the R4-R6 plateau at MfmaUtil~26-30%
// was LDS-BW-bound: ~1000 LDS cyc vs ~512 matrix cyc per block-kt).
// GATHER gemm1 reverts to R4-style A staging (128B/row VMEM segments,
// row-major sA + XOR frag reads) — R6's panel-gather shattered VMEM into
// 32B segments and cost 8 us/dispatch.
// ---------------------------------------------------------------------------

typedef __attribute__((ext_vector_type(8))) short short8;
typedef __attribute__((ext_vector_type(16))) float f32x16;
typedef __attribute__((ext_vector_type(4))) float floatv4;
typedef __attribute__((ext_vector_type(8))) unsigned short ushort8;

#define GLOAD_LDS16(g, l)                                                      \
  __builtin_amdgcn_global_load_lds(                                            \
      (const __attribute__((address_space(1))) void*)(g),                      \
      (__attribute__((address_space(3))) void*)(l), 16, 0, 0)

__device__ __forceinline__ unsigned short f2bf(float f) {
  unsigned int u = __float_as_uint(f);
  u += 0x7fffu + ((u >> 16) & 1u);  // RNE
  return (unsigned short)(u >> 16);
}
__device__ __forceinline__ float bf2f(unsigned short s) {
  return __uint_as_float(((unsigned int)s) << 16);
}

#define NNODES 100000
#define MTOT   300000
#define HD     512
#define NH     50000
#define LSTR   152   // L row stride in shorts: 304B = 19 x 16B (odd -> rotate)

// --- Wt in panel layout: per layer, per (nb,kt) panel of 1024 16B-slots -----
// slot s = (c>>1)*256 + ((row>>5)&3)*64 + (c&1)*32 + (row&31), c=k-granule 0..7
__global__ __launch_bounds__(256) void prep_w(const float* __restrict__ W1,
                                              const float* __restrict__ W2,
                                              const float* __restrict__ W3,
                                              unsigned short* __restrict__ Wt) {
  int t = blockIdx.x * 256 + threadIdx.x;  // < 3*512*512
  int layer = t >> 18;
  int r = t & 262143;
  int e = r & 7;
  int q16 = r >> 3;
  int s = q16 & 1023;
  int blk = q16 >> 10;        // 0..31
  int nb = blk >> 3, kt = blk & 7;
  int c = ((s >> 8) << 1) | ((s >> 5) & 1);
  int row = ((s >> 6) & 3) * 32 + (s & 31);
  int n = nb * 128 + row;
  int k = kt * 64 + c * 8 + e;
  const float* W = layer == 0 ? W1 : (layer == 1 ? W2 : W3);
  Wt[t] = f2bf(W[k * 512 + n]);
}

// --- hb = bf16(h) [50000 x 128], row-major ----------------------------------
__global__ __launch_bounds__(256) void prep_hb(const float* __restrict__ h,
                                               unsigned short* __restrict__ hb) {
  int t = blockIdx.x * 256 + threadIdx.x;  // < NH*16
  int v = t >> 4, c8 = (t & 15) * 8;
  const floatv4* hp = (const floatv4*)(h + (size_t)v * 128 + c8);
  floatv4 f0 = hp[0], f1 = hp[1];
  ushort8 o;
#pragma unroll
  for (int e = 0; e < 4; ++e) {
    o[e] = f2bf(f0[e]);
    o[4 + e] = f2bf(f1[e]);
  }
  *(ushort8*)(hb + (size_t)v * 128 + c8) = o;
}

__global__ __launch_bounds__(256) void init_out(float* __restrict__ out,
                                                const float* __restrict__ bo) {
  int t = blockIdx.x * 256 + threadIdx.x;
  if (t < 2 * NNODES) out[t] = bo[t & 1];
}

// --- GEMM: 128x128 tile, BK=64, K=512, 32x32x16 MFMA ------------------------
// GATHER: A staged via LDS from row-major hb (R4 pattern). Else: A read
// directly global->VGPR from panel-layout X. B always LDS (panel layout).
template <int GATHER, int FINAL>
__global__ __launch_bounds__(256, 4) void gemm_k(
    const unsigned short* __restrict__ A,   // GATHER ? hb(row-major) : X panel
    const int* __restrict__ idx,
    const unsigned short* __restrict__ Wt,  // panel layout
    const float* __restrict__ bias,
    unsigned short* __restrict__ Xout,      // panel layout
    float* __restrict__ out, const float* __restrict__ Wo,
    int mchunk0) {
  __shared__ __align__(16) char smem[39936];
  char* sB = smem;                       // 16384 (B tile, panel order)
  char* sA = smem + 16384;               // 16384 (GATHER only, row-major+XOR)
  int* sIdx = (int*)(smem + 32768);      // 2048  (GATHER only)
  float* sWo = (float*)(smem + 38912);   // 1024  (FINAL only)
  // epilogue L overlays smem[0..38912)

  const int t = threadIdx.x;
  int bx = blockIdx.x;
  // XCD swizzle: 4 col-blocks of one row-block land on one XCD.
  int xcd = bx & 7, tq = bx >> 3;
  int cbk = tq & 3;
  int rb = xcd + ((tq >> 2) << 3);
  int n0 = cbk * 128;
  int rb8 = rb * 8;
  int w = t >> 6, l = t & 63;
  int wmq = (w >> 1) * 2, wnq = (w & 1) * 2;   // 32-row-group bases
  int m32 = l & 31, half = l >> 5;
  int wm = wmq * 32;

  if (GATHER) {
    if (t < 128) {
      int m = mchunk0 + rb * 128 + t;
      unsigned um = (unsigned)m;
      unsigned n = um / 3u;
      int p = (int)(um - n * 3u);
      if (n >= NNODES) n = 0;  // padded tail rows: junk, guarded at output
      const unsigned pk0 = 0x320u, pk1 = 0x111u, pk2 = 0x032u, pk3 = 0x203u;
      int sh = p * 4;
      sIdx[t * 4 + 0] = idx[n * 4 + ((pk0 >> sh) & 0xFu)];
      sIdx[t * 4 + 1] = idx[n * 4 + ((pk1 >> sh) & 0xFu)];
      sIdx[t * 4 + 2] = idx[n * 4 + ((pk2 >> sh) & 0xFu)];
      sIdx[t * 4 + 3] = idx[n * 4 + ((pk3 >> sh) & 0xFu)];
    }
    __syncthreads();
  }

  f32x16 acc[2][2];
#pragma unroll
  for (int i = 0; i < 2; ++i)
#pragma unroll
    for (int j = 0; j < 2; ++j)
#pragma unroll
      for (int r = 0; r < 16; ++r) acc[i][j][r] = 0.f;

  for (int kt = 0; kt < 8; ++kt) {
    short8 afr[4][2];
    if (!GATHER) {
      // direct A-frag loads: lane-contiguous 1KB per (ks,i); issued before
      // B staging so the barrier's vmcnt(0) covers their latency.
      const unsigned short* ga = A + ((size_t)(rb8 + kt) * 1024) * 8;
#pragma unroll
      for (int ks = 0; ks < 4; ++ks)
#pragma unroll
        for (int i = 0; i < 2; ++i)
          afr[ks][i] = *(const short8*)(ga +
              (size_t)(ks * 256 + (wmq + i) * 64 + l) * 8);
    }
    {  // stage B (panel order: 4 contiguous streams)
      const unsigned short* gb = Wt + ((size_t)(cbk * 8 + kt) * 1024 + t) * 8;
#pragma unroll
      for (int i = 0; i < 4; ++i)
        GLOAD_LDS16(gb + (size_t)i * 2048, sB + (i * 256 + t) * 16);
    }
    if (GATHER) {  // stage A rows: 8 lanes x 16B = 128B contiguous per row
      int jblk = kt >> 1;
      int inner = (kt & 1) * 64;
#pragma unroll
      for (int i = 0; i < 4; ++i) {
        int s = i * 256 + t;
        int r = s >> 3;
        int cl = (s & 7) ^ (r & 7);
        int src = sIdx[r * 4 + jblk];
        GLOAD_LDS16(A + (size_t)src * 128 + inner + cl * 8, sA + s * 16);
      }
    }
    __syncthreads();
#pragma unroll
    for (int ks = 0; ks < 4; ++ks) {
      short8 bfr[2];
#pragma unroll
      for (int j = 0; j < 2; ++j)
        bfr[j] = *(const short8*)(sB + (ks * 256 + (wnq + j) * 64 + l) * 16);
      if (GATHER) {
        short8 ag[2];
        int cbp = ((ks << 1) + half) ^ (m32 & 7);
#pragma unroll
        for (int i = 0; i < 2; ++i)
          ag[i] = *(const short8*)(sA + (wm + i * 32 + m32) * 128 + cbp * 16);
#pragma unroll
        for (int i = 0; i < 2; ++i)
#pragma unroll
          for (int j = 0; j < 2; ++j)
            acc[i][j] = __builtin_amdgcn_mfma_f32_32x32x16_bf16(
                ag[i], bfr[j], acc[i][j], 0, 0, 0);
      } else {
#pragma unroll
        for (int i = 0; i < 2; ++i)
#pragma unroll
          for (int j = 0; j < 2; ++j)
            acc[i][j] = __builtin_amdgcn_mfma_f32_32x32x16_bf16(
                afr[ks][i], bfr[j], acc[i][j], 0, 0, 0);
      }
    }
    __syncthreads();
  }

  // Epilogue. 32x32 C/D: col = lane&31, row = (reg&3) + 8*(reg>>2) + 4*half.
  unsigned short* L = (unsigned short*)smem;
  if (FINAL && t < 256) sWo[t] = Wo[n0 * 2 + t];
#pragma unroll
  for (int i = 0; i < 2; ++i)
#pragma unroll
    for (int j = 0; j < 2; ++j) {
      int coll = wnq * 32 + j * 32 + m32;
      float bv = bias[n0 + coll];
#pragma unroll
      for (int r = 0; r < 16; ++r) {
        int rowl = wm + i * 32 + (r & 3) + 8 * (r >> 2) + 4 * half;
        float v = fmaxf(acc[i][j][r] + bv, 0.f);
        L[rowl * LSTR + coll] = f2bf(v);
      }
    }
  __syncthreads();

  if (!FINAL) {
    // panel-order coalesced stores: consecutive t -> consecutive 16B slots
#pragma unroll
    for (int v = 0; v < 8; ++v) {
      int chunk = v * 256 + t;          // 0..2047
      int ktsel = chunk >> 10;
      int s = chunk & 1023;
      int ks_l = s >> 8;
      int rowhi = (s >> 6) & 3;
      int hb_ = (s >> 5) & 1;
      int row = rowhi * 32 + (s & 31);
      int col_local = ktsel * 64 + (((ks_l << 1) | hb_) << 3);
      ushort8 val = *(const ushort8*)(L + row * LSTR + col_local);
      *(ushort8*)(Xout + ((size_t)(rb8 + 2 * cbk + ktsel) * 1024 + s) * 8) = val;
    }
  } else {
    int r2 = t >> 1, jo = t & 1;
    int grow = mchunk0 + rb * 128 + r2;
    if (grow < MTOT) {
      const unsigned short* Lr = L + r2 * LSTR;
      float s = 0.f;
#pragma unroll
      for (int cc = 0; cc < 128; cc += 2) {
        unsigned int pair = *(const unsigned int*)(Lr + cc);
        s += bf2f((unsigned short)(pair & 0xffffu)) * sWo[2 * cc + jo];
        s += bf2f((unsigned short)(pair >> 16)) * sWo[2 * cc + 2 + jo];
      }
      int node = grow / 3;
      atomicAdd(out + node * 2 + jo, s);
    }
  }
}

extern "C" void kernel_launch(void* const* d_in, const int* in_sizes, int n_in,
                              void* d_out, int out_size, void* d_ws,
                              size_t ws_size, hipStream_t stream) {
  const float* h  = (const float*)d_in[0];
  const int*   ix = (const int*)d_in[1];
  const float* W1 = (const float*)d_in[2];
  const float* b1 = (const float*)d_in[3];
  const float* W2 = (const float*)d_in[4];
  const float* b2 = (const float*)d_in[5];
  const float* W3 = (const float*)d_in[6];
  const float* b3 = (const float*)d_in[7];
  const float* Wo = (const float*)d_in[8];
  const float* bo = (const float*)d_in[9];
  float* out = (float*)d_out;

  unsigned short* ws = (unsigned short*)d_ws;
  unsigned short* Wt = ws;                  // 3*512*512 shorts (panel)
  unsigned short* hb = Wt + 786432;         // 50000*128 shorts (row-major)
  unsigned short* bufs = hb + 6400000;
  const size_t baseBytes = (786432ull + 6400000ull) * 2;

  // nodes per chunk: multiple of 2048 -> rows%6144==0 -> RB%48==0 (RB%8==0)
  size_t avail = ws_size > baseBytes ? ws_size - baseBytes : 0;
  size_t ncap = avail / (2ull * 3 * HD * sizeof(unsigned short));
  size_t nc = (ncap / 2048) * 2048;
  if (nc > 32768) nc = 32768;
  if (nc == 0) nc = 2048;  // best effort
  unsigned short* X1 = bufs;                // panel layout
  unsigned short* X2 = X1 + nc * 3 * HD;    // panel layout

  prep_w<<<3072, 256, 0, stream>>>(W1, W2, W3, Wt);
  prep_hb<<<NH * 16 / 256, 256, 0, stream>>>(h, hb);
  init_out<<<(2 * NNODES + 255) / 256, 256, 0, stream>>>(out, bo);

  for (size_t n0c = 0; n0c < NNODES; n0c += nc) {
    size_t remn = (size_t)NNODES - n0c;
    size_t ncp = remn < nc ? ((remn + 2047) / 2048) * 2048 : nc;
    int rows = (int)(ncp * 3);
    int RB = rows / 128;
    int m0 = (int)(3 * n0c);
    gemm_k<1, 0><<<RB * 4, 256, 0, stream>>>(hb, ix, Wt, b1, X1, nullptr,
                                             nullptr, m0);
    gemm_k<0, 0><<<RB * 4, 256, 0, stream>>>(X1, nullptr, Wt + 262144, b2, X2,
                                             nullptr, nullptr, m0);
    gemm_k<0, 1><<<RB * 4, 256, 0, stream>>>(X2, nullptr, Wt + 524288, b3,
                                             nullptr, out, Wo, m0);
  }
}